// Round 3
// baseline (175.037 us; speedup 1.0000x reference)
//
#include <hip/hip_runtime.h>
#include <stdint.h>

#define Cc 128

typedef __attribute__((ext_vector_type(4))) float f32x4;
typedef __attribute__((ext_vector_type(16))) float f32x16;
typedef __attribute__((ext_vector_type(8))) short s16x8;

__device__ __forceinline__ unsigned int asu(float f) { union { float f; unsigned int u; } v; v.f = f; return v.u; }
__device__ __forceinline__ float asf(unsigned int u) { union { unsigned int u; float f; } v; v.u = u; return v.f; }

__device__ __forceinline__ unsigned short f2bf_rne(float f) {
  unsigned int u = asu(f);
  unsigned int r = u + 0x7FFFu + ((u >> 16) & 1u);
  return (unsigned short)(r >> 16);
}

// pack two f32 -> bf16x2 dword (round-half-up via +0x8000, take high16)
__device__ __forceinline__ unsigned int pk2(float lo, float hi) {
  return __builtin_amdgcn_perm(asu(hi) + 0x8000u, asu(lo) + 0x8000u, 0x07060302u);
}

// one dword of packed bf16 pairs from A and B: relu(a+b) per half, repack
__device__ __forceinline__ unsigned int cvt1(unsigned int a, unsigned int b) {
  float alo = asf(a << 16), ahi = asf(a & 0xFFFF0000u);
  float blo = asf(b << 16), bhi = asf(b & 0xFFFF0000u);
  float lo = fmaxf(alo + blo, 0.f);
  float hi = fmaxf(ahi + bhi, 0.f);
  return pk2(lo, hi);
}

#define MFMA16(a, b, c) __builtin_amdgcn_mfma_f32_16x16x32_bf16((a), (b), (c), 0, 0, 0)
#define MFMA32(a, b, c) __builtin_amdgcn_mfma_f32_32x32x16_bf16((a), (b), (c), 0, 0, 0)

// ---------------------------------------------------------------------------
// pack_kernel:
//  W1p (16x16 frag): (kt,ct,l,j) <- W1cat[kt*32 + (l>>4)*8 + j][ct*16 + (l&15)]
//  W2p (32x32 frag): (kt,ct,l,j) <- W2[kt*16 + (l>>5)*8 + j][ct*32 + (l&31)]
//  W3p (16x16 frag): as W1p shape but 256x128
//  t3 = b3 + c3, u3 = 16*c3, c3 = relu(b2) @ W3
// ---------------------------------------------------------------------------
__global__ void pack_kernel(const float* __restrict__ W1,
                            const float* __restrict__ W2,
                            const float* __restrict__ W3,
                            const float* __restrict__ b2,
                            const float* __restrict__ b3,
                            unsigned short* __restrict__ W1p,
                            unsigned short* __restrict__ W2p,
                            unsigned short* __restrict__ W3p,
                            float* __restrict__ t3v,
                            float* __restrict__ u3v) {
  int blk = blockIdx.x, t = threadIdx.x;
  if (blk < 32) {
    // W1p: K=128, 512 packed cols (0..255 = W1_top out-cols, 256..511 = W1_bot)
    int f = blk * 256 + t;
    int l = f & 63, ct = (f >> 6) & 31, kt = f >> 11;
    int col = ct * 16 + (l & 15);
    int k0 = kt * 32 + ((l >> 4) << 3);
    unsigned short tmp[8];
#pragma unroll
    for (int j = 0; j < 8; ++j) {
      int k = k0 + j;
      float v = (col < 256) ? W1[k * 256 + col] : W1[(128 + k) * 256 + (col - 256)];
      tmp[j] = f2bf_rne(v);
    }
    *(uint4*)(W1p + f * 8) = *(uint4*)tmp;
  } else if (blk < 64) {
    // W2p: 256x256, 32x32-fragment layout: kt 0..15 (K=16 each), ct 0..7
    int f = (blk - 32) * 256 + t;
    int l = f & 63, ct = (f >> 6) & 7, kt = f >> 9;
    int col = ct * 32 + (l & 31);
    int k0 = kt * 16 + ((l >> 5) << 3);
    unsigned short tmp[8];
#pragma unroll
    for (int j = 0; j < 8; ++j) tmp[j] = f2bf_rne(W2[(k0 + j) * 256 + col]);
    *(uint4*)(W2p + f * 8) = *(uint4*)tmp;
  } else if (blk < 80) {
    // W3p: 256x128, 16x16-fragment layout
    int f = (blk - 64) * 256 + t;
    int l = f & 63, ct = (f >> 6) & 7, kt = f >> 9;
    int col = ct * 16 + (l & 15);
    int k0 = kt * 32 + ((l >> 4) << 3);
    unsigned short tmp[8];
#pragma unroll
    for (int j = 0; j < 8; ++j) tmp[j] = f2bf_rne(W3[(k0 + j) * 128 + col]);
    *(uint4*)(W3p + f * 8) = *(uint4*)tmp;
  } else {
    // t3/u3: col-parallel (coalesced); 2 threads per col, halves reduced in LDS
    __shared__ float part[256];
    if (t < 256) {
      int col = t & 127, half = t >> 7;
      float s = 0.f;
      for (int j = half * 128; j < half * 128 + 128; ++j)
        s += fmaxf(b2[j], 0.f) * W3[j * 128 + col];
      part[t] = s;
    }
    __syncthreads();
    if (t < 128) {
      float c3 = part[t] + part[t + 128];
      t3v[t] = b3[t] + c3;
      u3v[t] = 16.f * c3;
    }
  }
}

// ---------------------------------------------------------------------------
// k1: per-node  A = feats@W1_top + b1  (cols 0..255),  Bc = feats@W1_bot.
// Reads f32 feats directly. Epilogue: LDS transpose -> coalesced 16B stores.
// ---------------------------------------------------------------------------
__global__ __launch_bounds__(256, 2) void k1_gemm(
    const float* __restrict__ feats,
    const unsigned short* __restrict__ W1p,
    const float* __restrict__ b1,
    unsigned short* __restrict__ A_ws,
    unsigned short* __restrict__ B_ws) {
  __shared__ __attribute__((aligned(16))) unsigned short cs[64 * 512];  // 64KB
  char* cb = (char*)cs;
  int m0 = blockIdx.x * 64;
  int t = threadIdx.x, w = t >> 6, l = t & 63, lr = l & 15, lg = l >> 4;
  f32x4 zero4 = {0.f, 0.f, 0.f, 0.f};
  f32x4 acc[4][8];
#pragma unroll
  for (int i = 0; i < 4; ++i)
#pragma unroll
    for (int j = 0; j < 8; ++j) acc[i][j] = zero4;

  for (int kt = 0; kt < 4; ++kt) {
    s16x8 a[4];
#pragma unroll
    for (int rt = 0; rt < 4; ++rt) {
      const float* fr = feats + (m0 + rt * 16 + lr) * 128 + kt * 32 + lg * 8;
      float4 f0 = *(const float4*)fr;
      float4 f1 = *(const float4*)(fr + 4);
      uint4 pk;
      pk.x = pk2(f0.x, f0.y);
      pk.y = pk2(f0.z, f0.w);
      pk.z = pk2(f1.x, f1.y);
      pk.w = pk2(f1.z, f1.w);
      *(uint4*)&a[rt] = pk;
    }
#pragma unroll
    for (int ctl = 0; ctl < 8; ++ctl) {
      s16x8 bf = *(const s16x8*)(W1p + (((kt * 32) + (w * 8 + ctl)) * 64 + l) * 8);
#pragma unroll
      for (int rt = 0; rt < 4; ++rt)
        acc[rt][ctl] = MFMA16(a[rt], bf, acc[rt][ctl]);
    }
  }

  // epilogue -> LDS [node 0..63][ch 0..511] bf16, XOR-swizzled 16B chunks
#pragma unroll
  for (int ctl = 0; ctl < 8; ++ctl) {
    int col = w * 128 + ctl * 16 + lr;
    float bias = (col < 256) ? b1[col] : 0.f;
#pragma unroll
    for (int rt = 0; rt < 4; ++rt) {
#pragma unroll
      for (int reg = 0; reg < 4; ++reg) {
        int node = rt * 16 + lg * 4 + reg;
        float v = acc[rt][ctl][reg] + bias;
        unsigned short bv = (unsigned short)((asu(v) + 0x8000u) >> 16);
        *(unsigned short*)(cb + ((node * 1024 + col * 2) ^ ((node & 7) << 4))) = bv;
      }
    }
  }
  __syncthreads();
#pragma unroll
  for (int i = 0; i < 16; ++i) {
    int row = i * 4 + w;
    uint4 v = *(const uint4*)(cb + row * 1024 + ((l * 16) ^ ((row & 7) << 4)));
    int node = m0 + row;
    unsigned short* dst = (l < 32) ? (A_ws + node * 256 + l * 8)
                                   : (B_ws + node * 256 + (l - 32) * 8);
    *(uint4*)dst = v;
  }
}

// ---------------------------------------------------------------------------
// k2: fused edge MLP. wg = 4 queries x 16 neighbors = 64 edge-rows, 512 thr.
// GEMM1 uses 32x32x16 MFMA: wave w -> cols [w*32,w*32+32), 2 row-tiles of 32.
// acc = 2 x f32x16 = 32 VGPR (no spills). Invalid rows zeroed in staging;
// analytic correction (t3/u3) in the final epilogue.
// ---------------------------------------------------------------------------
__global__ __launch_bounds__(512, 4) void k2_fused(
    const unsigned short* __restrict__ A_ws,
    const unsigned short* __restrict__ B_ws,
    const unsigned short* __restrict__ W2p,
    const unsigned short* __restrict__ W3p,
    const int* __restrict__ n_idxs,
    const int* __restrict__ valid,
    const float* __restrict__ b2,
    const float* __restrict__ t3v,
    const float* __restrict__ u3v,
    float* __restrict__ out) {
  __shared__ __attribute__((aligned(16))) unsigned short h1s[64 * 256];  // 32KB
  __shared__ __attribute__((aligned(16))) unsigned short gs[16 * 264];   // 8.25KB
  __shared__ float nvf[4];
  char* h1b = (char*)h1s;
  char* gb = (char*)gs;

  int t = threadIdx.x, w = t >> 6, l = t & 63;
  int wg = blockIdx.x;
  int qbase = wg * 4, ebase = wg * 64;
  int bN = qbase & ~4095;  // batch*N

  // zero gs rows 4..15 so GEMM3's 16-row A-fragment is clean
  if (t < 384) {
    int row = 4 + (t >> 5), ch = t & 31;
    *(f32x4*)(gb + row * 528 + ch * 16) = f32x4{0.f, 0.f, 0.f, 0.f};
  }
  if (t < 4) {
    int s = 0;
#pragma unroll
    for (int k = 0; k < 16; ++k) s += valid[ebase + t * 16 + k];
    nvf[t] = (float)s;
  }

  // ---- stage h1[64][256] = relu(A[q]+B[idx]) bf16, invalid rows zeroed ----
  // thread t -> row r=t>>3; chunk c = (t&7) + 8*i  (each 8-lane phase covers
  // 128 contiguous bytes both in global (coalesced) and LDS (conflict-free))
  {
    int r = t >> 3, c8 = t & 7;
    int nb = n_idxs[ebase + r];
    int vld = valid[ebase + r];
    const unsigned short* pa = A_ws + (qbase + (r >> 4)) * 256;
    const unsigned short* pb = B_ws + (bN + nb) * 256;
    int swz = (r & 7) << 4;
#pragma unroll
    for (int i = 0; i < 4; ++i) {
      int ch = c8 + i * 8;
      uint4 av = *(const uint4*)(pa + ch * 8);
      uint4 bv = *(const uint4*)(pb + ch * 8);
      uint4 o;
      o.x = cvt1(av.x, bv.x);
      o.y = cvt1(av.y, bv.y);
      o.z = cvt1(av.z, bv.z);
      o.w = cvt1(av.w, bv.w);
      if (!vld) { o.x = 0u; o.y = 0u; o.z = 0u; o.w = 0u; }
      *(uint4*)(h1b + ((r * 512 + ch * 16) ^ swz)) = o;
    }
  }
  __syncthreads();

  // ---- GEMM1 (32x32x16): rows 0-31 / 32-63, cols w*32..w*32+32 ----
  f32x16 acc0 = {0.f,0.f,0.f,0.f,0.f,0.f,0.f,0.f,0.f,0.f,0.f,0.f,0.f,0.f,0.f,0.f};
  f32x16 acc1 = acc0;
  {
    int hi = l >> 5, col = l & 31;
    int row0 = col, row1 = 32 + col;
    int base0 = row0 * 512, sz0 = (row0 & 7) << 4;
    int base1 = row1 * 512, sz1 = (row1 & 7) << 4;
#pragma unroll
    for (int kt = 0; kt < 16; ++kt) {
      int kb = kt * 32 + hi * 16;
      s16x8 a0 = *(const s16x8*)(h1b + ((base0 + kb) ^ sz0));
      s16x8 a1 = *(const s16x8*)(h1b + ((base1 + kb) ^ sz1));
      s16x8 bf = *(const s16x8*)(W2p + ((kt * 8 + w) * 64 + l) * 8);
      acc0 = MFMA32(a0, bf, acc0);
      acc1 = MFMA32(a1, bf, acc1);
    }
  }

  // ---- epilogue: +b2, relu, sum 16 rows per query ----
  // C/D 32x32: col=l&31, row=(reg&3)+8*(reg>>2)+4*(l>>5); query = row>>4:
  // regs 0..7 -> first query of the tile, regs 8..15 -> second.
  {
    int col = l & 31;
    float bias = b2[w * 32 + col];
    float s0 = 0.f, s1 = 0.f, s2 = 0.f, s3 = 0.f;
#pragma unroll
    for (int g = 0; g < 8; ++g) {
      s0 += fmaxf(acc0[g] + bias, 0.f);
      s1 += fmaxf(acc0[8 + g] + bias, 0.f);
      s2 += fmaxf(acc1[g] + bias, 0.f);
      s3 += fmaxf(acc1[8 + g] + bias, 0.f);
    }
    s0 += __shfl_xor(s0, 32);
    s1 += __shfl_xor(s1, 32);
    s2 += __shfl_xor(s2, 32);
    s3 += __shfl_xor(s3, 32);
    if (l < 32) {
      int cb2 = (w * 32 + col) * 2;
      *(unsigned short*)(gb + 0 * 528 + cb2) = f2bf_rne(s0);
      *(unsigned short*)(gb + 1 * 528 + cb2) = f2bf_rne(s1);
      *(unsigned short*)(gb + 2 * 528 + cb2) = f2bf_rne(s2);
      *(unsigned short*)(gb + 3 * 528 + cb2) = f2bf_rne(s3);
    }
  }
  __syncthreads();

  // ---- GEMM3 (16x16x32): g[16x256] @ W3p; wave w -> out cols w*16.. ----
  {
    int lr = l & 15, lg = l >> 4;
    f32x4 acc3 = {0.f, 0.f, 0.f, 0.f};
#pragma unroll
    for (int kt = 0; kt < 8; ++kt) {
      s16x8 a = *(const s16x8*)(gb + lr * 528 + kt * 64 + lg * 16);
      s16x8 bf = *(const s16x8*)(W3p + ((kt * 8 + w) * 64 + l) * 8);
      acc3 = MFMA16(a, bf, acc3);
    }
    if (lg == 0) {
      int col3 = w * 16 + lr;
      float tt = t3v[col3], uu = u3v[col3];
#pragma unroll
      for (int reg = 0; reg < 4; ++reg)
        out[(qbase + reg) * Cc + col3] = acc3[reg] + nvf[reg] * tt - uu;
    }
  }
}

// ---------------------------------------------------------------------------
extern "C" void kernel_launch(void* const* d_in, const int* in_sizes, int n_in,
                              void* d_out, int out_size, void* d_ws, size_t ws_size,
                              hipStream_t stream) {
  // inputs: keys(0) points(1) feats(2) n_idxs(3) neighbor_valid(4)
  //         W1(5) b1(6) W2(7) b2(8) W3(9) b3(10)
  const float* feats = (const float*)d_in[2];
  const int* n_idxs = (const int*)d_in[3];
  const int* valid = (const int*)d_in[4];
  const float* W1 = (const float*)d_in[5];
  const float* b1 = (const float*)d_in[6];
  const float* W2 = (const float*)d_in[7];
  const float* b2 = (const float*)d_in[8];
  const float* W3 = (const float*)d_in[9];
  const float* b3 = (const float*)d_in[10];
  float* out = (float*)d_out;

  char* ws = (char*)d_ws;
  unsigned short* A_ws = (unsigned short*)(ws);                       // 8 MB
  unsigned short* B_ws = (unsigned short*)(ws + (8u << 20));          // 8 MB
  unsigned short* W1p  = (unsigned short*)(ws + (16u << 20));         // 128 KB
  unsigned short* W2p  = (unsigned short*)(ws + (16u << 20) + (128u << 10));  // 128 KB
  unsigned short* W3p  = (unsigned short*)(ws + (16u << 20) + (256u << 10));  // 64 KB
  float* t3v = (float*)(ws + (16u << 20) + (320u << 10));             // 512 B
  float* u3v = (float*)(ws + (16u << 20) + (321u << 10));             // 512 B

  pack_kernel<<<81, 256, 0, stream>>>(W1, W2, W3, b2, b3, W1p, W2p, W3p, t3v, u3v);
  k1_gemm<<<256, 256, 0, stream>>>(feats, W1p, b1, A_ws, B_ws);
  k2_fused<<<4096, 512, 0, stream>>>(A_ws, B_ws, W2p, W3p, n_idxs, valid, b2, t3v, u3v, out);
}